// Round 5
// baseline (286.078 us; speedup 1.0000x reference)
//
// AttentionModel: fused QKV projection + causal softmax attention, MI355X/gfx950.
// Round 5: kill auxiliary traffic.
//  - k_cvtin and k_trans DELETED. k_proj reads fp32 q/k/v directly: A staged as
//    raw fp32 via global_load_lds (32 KB As, swizzled 16-B groups), converted to
//    f16 at fragment-read (2x ds_read_b128 + packed cvt). B (f16 weights) staged
//    as before. 48 KB LDS.
//  - Coalesced epilogues: proj & scores stage the C-tile in reused LDS, then
//    store 256-B rows (16 lanes x 16 B). Fixes the measured 1.9x HBM write
//    amplification (proj WRITE_SIZE 90 MB vs 48 ideal). proj z==2 also emits
//    Vt[d][s] from the LDS tile (replaces k_trans).
//  - GEMM core (m97 shape, R4-verified): single As+Bs, 2 barriers/iter, pure
//    global_load_lds staging; XCD-locality swizzles kept (R3-verified).
// ws layout (bytes): P 0..64M | Qb 64M | Kb 80M | Vb 96M | Vt 112M | Wf16 128M

#include <hip/hip_runtime.h>
#include <stdint.h>
#include <stddef.h>
#include <math.h>

typedef _Float16 half8 __attribute__((ext_vector_type(8)));
typedef float f32x4 __attribute__((ext_vector_type(4)));

#define SCALE_QK 0.04419417382415922f  // 1/sqrt(512)

__device__ __forceinline__ void gload16(const void* g, void* lds) {
  __builtin_amdgcn_global_load_lds(
      (const __attribute__((address_space(1))) void*)g,
      (__attribute__((address_space(3))) void*)lds,
      16, 0, 0);
}

// m97-style K-loop: C[128x128] = A[128xK] * B^T (B stored [N][K]), f16 MFMA.
// A_F32=false: As is 128x64 f16 (16 KB), layout: row r, 8-half group g at slot
//   g^(r&7) (halfword addr r*64 + slot*8).
// A_F32=true:  As is 128x64 f32 (32 KB), layout: row r, 4-float group g (0..15)
//   at slot g^((r&7)<<1) (float addr r*64 + slot*4); converted to f16 at
//   frag-read time. Swizzles keep even/odd group pairs adjacent.
template<bool A_F32>
__device__ __forceinline__ void run_kloop(const void* Aptr, const _Float16* B,
                                          int lda, int ldb, int kIters,
                                          void* AsRaw, _Float16* Bs,
                                          f32x4 (&acc)[4][4])
{
  const int tid  = threadIdx.x;
  const int lane = tid & 63;
  const int w    = tid >> 6;
  const int wm   = w >> 1, wn = w & 1;
  const int srow = tid >> 3;          // f16 staging row helper
  const int sg   = tid & 7;
  const int swz  = sg ^ (srow & 7);
  const int fr   = lane & 15;
  const int fq   = lane >> 4;
  const int fx   = lane & 7;

  auto stage = [&](int it) {
    const int k0 = it * 64;
    if constexpr (A_F32) {
      const float* A = (const float*)Aptr;
      float* As32 = (float*)AsRaw;
      #pragma unroll
      for (int i = 0; i < 8; ++i) {
        const int n = i * 4 + w;              // wave-uniform chunk id
        const int row = n * 4 + (lane >> 4);  // 4 rows per 1-KB chunk
        const int g = (lane & 15) ^ ((row & 7) << 1);
        gload16(A + (size_t)row * lda + k0 + g * 4, As32 + n * 256);
      }
    } else {
      const _Float16* A = (const _Float16*)Aptr;
      _Float16* As16 = (_Float16*)AsRaw;
      #pragma unroll
      for (int i = 0; i < 4; ++i)
        gload16(A + (size_t)(i*32 + srow) * lda + (k0 + swz*8), As16 + i*2048 + w*512);
    }
    #pragma unroll
    for (int i = 0; i < 4; ++i)
      gload16(B + (size_t)(i*32 + srow) * ldb + (k0 + swz*8), Bs + i*2048 + w*512);
  };

  auto compute = [&]() {
    #pragma unroll
    for (int ks = 0; ks < 2; ++ks) {
      half8 av[4], bv[4];
      #pragma unroll
      for (int i = 0; i < 4; ++i) {
        const int r = wm*64 + i*16 + fr;
        if constexpr (A_F32) {
          const float* As32 = (const float*)AsRaw;
          const int m = ks*4 + fq;
          const int g0 = (2*m) ^ ((r & 7) << 1);   // even; g0+1 holds odd group
          const float* pa = As32 + r*64 + g0*4;
          f32x4 a0 = *(const f32x4*)pa;
          f32x4 a1 = *(const f32x4*)(pa + 4);
          half8 h;
          h[0]=(_Float16)a0[0]; h[1]=(_Float16)a0[1]; h[2]=(_Float16)a0[2]; h[3]=(_Float16)a0[3];
          h[4]=(_Float16)a1[0]; h[5]=(_Float16)a1[1]; h[6]=(_Float16)a1[2]; h[7]=(_Float16)a1[3];
          av[i] = h;
        } else {
          const _Float16* As16 = (const _Float16*)AsRaw;
          av[i] = *(const half8*)(As16 + r*64 + (((ks*4+fq) ^ fx))*8);
        }
        bv[i] = *(const half8*)(Bs + (wn*64 + i*16 + fr)*64 + (((ks*4+fq) ^ fx))*8);
      }
      #pragma unroll
      for (int i = 0; i < 4; ++i) {
        #pragma unroll
        for (int j = 0; j < 4; ++j)
          acc[i][j] = __builtin_amdgcn_mfma_f32_16x16x32_f16(av[i], bv[j], acc[i][j], 0, 0, 0);
      }
    }
  };

  stage(0);
  __syncthreads();                 // drain gloads
  for (int it = 0; ; ) {
    compute();
    if (++it >= kIters) break;
    __syncthreads();               // LDS readers done
    stage(it);
    __syncthreads();               // drain gloads
  }
}

// ---- weights fp32 -> f16 (3 x 512x512 concatenated) ----
__global__ __launch_bounds__(256) void k_cvtw(const float* __restrict__ Wq,
                                              const float* __restrict__ Wk,
                                              const float* __restrict__ Wv,
                                              _Float16* __restrict__ Wb)
{
  const int t = blockIdx.x * 256 + threadIdx.x;
  const int base = t * 8;                 // 786432 total elems
  const int z = base >> 18;               // 262144 per matrix
  const int off = base & 262143;
  const float* src = (z == 0) ? Wq : ((z == 1) ? Wk : Wv);
  f32x4 a = *(const f32x4*)(src + off);
  f32x4 b = *(const f32x4*)(src + off + 4);
  half8 h;
  h[0]=(_Float16)a[0]; h[1]=(_Float16)a[1]; h[2]=(_Float16)a[2]; h[3]=(_Float16)a[3];
  h[4]=(_Float16)b[0]; h[5]=(_Float16)b[1]; h[6]=(_Float16)b[2]; h[7]=(_Float16)b[3];
  *(half8*)(Wb + base) = h;
}

// ---- projections: X[16384x512](fp32, direct) @ W^T + bias -> f16 (+Vt for z=2) ----
// 1D grid 1536: xcd = bid%8; i = bid/8; panel p = xcd*48 + i/4; nt = i%4;
// z = p/128, mt = p%128. All 4 nt-siblings of a panel share an XCD's L2.
__global__ __launch_bounds__(256) void k_proj(const float* __restrict__ q,
                                              const float* __restrict__ k,
                                              const float* __restrict__ v,
                                              const _Float16* __restrict__ Wb,
                                              const float* __restrict__ bq,
                                              const float* __restrict__ bk,
                                              const float* __restrict__ bv,
                                              _Float16* __restrict__ Qb,
                                              _Float16* __restrict__ Kb,
                                              _Float16* __restrict__ Vb,
                                              _Float16* __restrict__ Vt)
{
  __shared__ __align__(16) _Float16 sh[24576];  // 48 KB: As32 32K | Bs 16K; Cs reuses 32K
  float*    As32 = (float*)sh;
  _Float16* Bs   = sh + 16384;
  _Float16* Cs   = sh;

  const int bid = blockIdx.x;
  const int xcd = bid & 7, ii = bid >> 3;
  const int p = xcd * 48 + (ii >> 2);
  const int nt = ii & 3;
  const int z = p >> 7, mt = p & 127;

  const float* A   = (z == 0) ? q  : (z == 1) ? k  : v;
  const float* bia = (z == 0) ? bq : (z == 1) ? bk : bv;
  const _Float16* B = Wb + (size_t)z * 512 * 512;
  _Float16* C      = (z == 0) ? Qb : (z == 1) ? Kb : Vb;

  f32x4 acc[4][4] = {};
  run_kloop<true>(A + (size_t)mt*128*512, B + (size_t)nt*128*512, 512, 512, 8, As32, Bs, acc);

  const int tid = threadIdx.x;
  const int lane = tid & 63, w = tid >> 6;
  const int wm = w >> 1, wn = w & 1;
  const int fr = lane & 15, fq = lane >> 4;   // C/D: col=lane&15, row=(lane>>4)*4+reg
  const int row0 = mt * 128, col0 = nt * 128;

  __syncthreads();  // kloop LDS reads done; reuse as Cs
  #pragma unroll
  for (int j = 0; j < 4; ++j) {
    const float bval = bia[col0 + wn*64 + j*16 + fr];
    #pragma unroll
    for (int i = 0; i < 4; ++i) {
      #pragma unroll
      for (int r = 0; r < 4; ++r)
        Cs[(wm*64 + i*16 + fq*4 + r) * 128 + wn*64 + j*16 + fr] =
            (_Float16)(acc[i][j][r] + bval);
    }
  }
  __syncthreads();

  const int rr = tid >> 4, cc = tid & 15;
  #pragma unroll
  for (int m2 = 0; m2 < 8; ++m2) {
    const int r = m2*16 + rr;
    half8 val = *(const half8*)(Cs + r*128 + cc*8);
    *(half8*)(C + (size_t)(row0 + r)*512 + col0 + cc*8) = val;
  }
  if (z == 2) {
    const int b = row0 >> 11, s0 = row0 & 2047;
    #pragma unroll
    for (int m2 = 0; m2 < 8; ++m2) {
      const int d = m2*16 + rr;     // 0..127 within tile
      half8 vv;
      #pragma unroll
      for (int x = 0; x < 8; ++x) vv[x] = Cs[(cc*8 + x)*128 + d];
      *(half8*)(Vt + ((size_t)b*512 + col0 + d)*2048 + s0 + cc*8) = vv;
    }
  }
}

// ---- scores: S = Q K^T * scale, coalesced LDS-staged epilogue ----
// 1D grid 1088: b = bid%8 (-> XCD b); t = bid/8 in [0,136) triangular-decoded
// to (qt,kt), kt<=qt. Per-batch Q+K (4MB) is L2-resident on its XCD.
__global__ __launch_bounds__(256) void k_scores(const _Float16* __restrict__ Qb,
                                                const _Float16* __restrict__ Kb,
                                                _Float16* __restrict__ P)
{
  __shared__ __align__(16) _Float16 sh[16384];  // 32 KB: As 16K | Bs 16K; Cs reuses all
  _Float16* As = sh;
  _Float16* Bs = sh + 8192;
  _Float16* Cs = sh;

  const int bid = blockIdx.x;
  const int b = bid & 7;
  const int t = bid >> 3;
  int qt = (int)((sqrtf(8.0f * (float)t + 1.0f) - 1.0f) * 0.5f);
  int base = (qt * (qt + 1)) >> 1;
  if (t < base)                { --qt; base = (qt * (qt + 1)) >> 1; }
  else if (t >= base + qt + 1) { ++qt; base = (qt * (qt + 1)) >> 1; }
  const int kt = t - base;

  f32x4 acc[4][4] = {};
  run_kloop<false>(Qb + ((size_t)b*2048 + qt*128)*512,
                   Kb + ((size_t)b*2048 + kt*128)*512,
                   512, 512, 8, As, Bs, acc);

  const int tid = threadIdx.x;
  const int lane = tid & 63, w = tid >> 6;
  const int wm = w >> 1, wn = w & 1;
  const int fr = lane & 15, fq = lane >> 4;

  __syncthreads();
  #pragma unroll
  for (int i = 0; i < 4; ++i) {
    #pragma unroll
    for (int j = 0; j < 4; ++j) {
      #pragma unroll
      for (int r = 0; r < 4; ++r)
        Cs[(wm*64 + i*16 + fq*4 + r) * 128 + wn*64 + j*16 + fr] =
            (_Float16)(acc[i][j][r] * SCALE_QK);
    }
  }
  __syncthreads();

  const int rr = tid >> 4, cc = tid & 15;
  #pragma unroll
  for (int m2 = 0; m2 < 8; ++m2) {
    const int r = m2*16 + rr;
    half8 val = *(const half8*)(Cs + r*128 + cc*8);
    *(half8*)(P + ((size_t)b*2048 + qt*128 + r)*2048 + kt*128 + cc*8) = val;
  }
}

// ---- in-place causal row softmax; one wave per row; online max/sum ----
__global__ __launch_bounds__(256) void k_softmax(_Float16* __restrict__ P)
{
  const int lane = threadIdx.x & 63;
  const int row  = blockIdx.x * 4 + (threadIdx.x >> 6);  // 0..16383 (= b*2048+q)
  const int qIdx = row & 2047;
  _Float16* p = P + (size_t)row * 2048;
  const int L    = qIdx + 1;                    // causal length
  const int Lpad = ((qIdx >> 7) + 1) * 128;     // PV kernel reads up to here

  float m = -1e30f, s = 0.f;
  for (int i0 = lane * 8; i0 < L; i0 += 512) {
    float xv[8];
    if (i0 + 8 <= L) {
      half8 x = *(const half8*)(p + i0);
      #pragma unroll
      for (int j = 0; j < 8; ++j) xv[j] = (float)x[j];
    } else {
      #pragma unroll
      for (int j = 0; j < 8; ++j) xv[j] = (i0 + j < L) ? (float)p[i0 + j] : -1e30f;
    }
    float cm = xv[0];
    #pragma unroll
    for (int j = 1; j < 8; ++j) cm = fmaxf(cm, xv[j]);
    const float mn = fmaxf(m, cm);
    float cs = 0.f;
    #pragma unroll
    for (int j = 0; j < 8; ++j) cs += __expf(xv[j] - mn);  // exp(-huge)=0 for pads
    s = s * __expf(m - mn) + cs;
    m = mn;
  }
  #pragma unroll
  for (int d = 1; d < 64; d <<= 1) {
    const float mo = __shfl_xor(m, d, 64);
    const float so = __shfl_xor(s, d, 64);
    const float mn = fmaxf(m, mo);
    s = s * __expf(m - mn) + so * __expf(mo - mn);
    m = mn;
  }
  const float inv = 1.0f / s;

  for (int i0 = lane * 8; i0 < Lpad; i0 += 512) {
    half8 o;
    if (i0 + 8 <= L) {
      half8 x = *(const half8*)(p + i0);
      #pragma unroll
      for (int j = 0; j < 8; ++j) o[j] = (_Float16)(__expf((float)x[j] - m) * inv);
    } else {
      #pragma unroll
      for (int j = 0; j < 8; ++j) {
        const int idx = i0 + j;
        o[j] = (idx < L) ? (_Float16)(__expf((float)p[idx] - m) * inv) : (_Float16)0.f;
      }
    }
    *(half8*)(p + i0) = o;
  }
}

// ---- out = P @ V  (B-operand = Vt[d][s]), causal K-extent ----
// 1D grid 512: b = bid%8 (-> XCD b); r = bid/8 in [0,64): qi=r/4 interleaved
// long/short for balance, dt=r%4. Out stores: 16 lanes x 4 B = 64 B lines, OK direct.
__global__ __launch_bounds__(256) void k_pv(const _Float16* __restrict__ P,
                                            const _Float16* __restrict__ Vt,
                                            float* __restrict__ Out)
{
  __shared__ __align__(16) _Float16 As[8192];
  __shared__ __align__(16) _Float16 Bs[8192];
  const int bid = blockIdx.x;
  const int b = bid & 7;
  const int r0 = bid >> 3;
  const int qi = r0 >> 2, dt = r0 & 3;
  const int qt = (qi & 1) ? (15 - (qi >> 1)) : (qi >> 1);

  f32x4 acc[4][4] = {};
  run_kloop<false>(P  + ((size_t)b*2048 + qt*128)*2048,
                   Vt + ((size_t)b*512  + dt*128)*2048,
                   2048, 2048, (qt + 1) * 2, As, Bs, acc);
  const int lane = threadIdx.x & 63, w = threadIdx.x >> 6;
  const int wm = w >> 1, wn = w & 1;
  const int fr = lane & 15, fq = lane >> 4;
  #pragma unroll
  for (int i = 0; i < 4; ++i) {
    const int row = qt*128 + wm*64 + i*16 + fq*4;
    #pragma unroll
    for (int j = 0; j < 4; ++j) {
      const int col = dt*128 + wn*64 + j*16 + fr;
      #pragma unroll
      for (int r = 0; r < 4; ++r)
        Out[((size_t)b*2048 + row + r) * 512 + col] = acc[i][j][r];
    }
  }
}

extern "C" void kernel_launch(void* const* d_in, const int* in_sizes, int n_in,
                              void* d_out, int out_size, void* d_ws, size_t ws_size,
                              hipStream_t stream) {
  (void)in_sizes; (void)n_in; (void)out_size;
  const float* q  = (const float*)d_in[0];
  const float* k  = (const float*)d_in[1];
  const float* v  = (const float*)d_in[2];
  // d_in[3] = causal mask: always tril per setup; implemented structurally.
  const float* Wq = (const float*)d_in[4];
  const float* bq = (const float*)d_in[5];
  const float* Wk = (const float*)d_in[6];
  const float* bk = (const float*)d_in[7];
  const float* Wv = (const float*)d_in[8];
  const float* bv = (const float*)d_in[9];

  const size_t OFF_P  = 0;
  const size_t OFF_Q  = (size_t)64 << 20;
  const size_t OFF_K  = (size_t)80 << 20;
  const size_t OFF_V  = (size_t)96 << 20;
  const size_t OFF_VT = (size_t)112 << 20;
  const size_t OFF_W  = (size_t)128 << 20;
  const size_t NEEDED = OFF_W + (size_t)3 * 512 * 512 * sizeof(_Float16);
  if (ws_size < NEEDED) return;  // diagnostic: poison-level absmax => ws too small

  char* ws = (char*)d_ws;
  _Float16* P  = (_Float16*)(ws + OFF_P);
  _Float16* Qb = (_Float16*)(ws + OFF_Q);
  _Float16* Kb = (_Float16*)(ws + OFF_K);
  _Float16* Vb = (_Float16*)(ws + OFF_V);
  _Float16* Vt = (_Float16*)(ws + OFF_VT);
  _Float16* Wb = (_Float16*)(ws + OFF_W);
  float* Out = (float*)d_out;

  k_cvtw   <<<dim3(384),  dim3(256), 0, stream>>>(Wq, Wk, Wv, Wb);
  k_proj   <<<dim3(1536), dim3(256), 0, stream>>>(q, k, v, Wb, bq, bk, bv, Qb, Kb, Vb, Vt);
  k_scores <<<dim3(1088), dim3(256), 0, stream>>>(Qb, Kb, P);
  k_softmax<<<dim3(4096), dim3(256), 0, stream>>>(P);
  k_pv     <<<dim3(512),  dim3(256), 0, stream>>>(P, Vt, Out);
}